// Round 1
// baseline (254.624 us; speedup 1.0000x reference)
//
#include <hip/hip_runtime.h>

// ---------------------------------------------------------------------------
// GCN 2-layer encoder for MI355X.
//   deg/dinv -> CSR (count, scan, fill) -> GEMM1(+dinv scale) -> AGG1(+b1,relu)
//   -> GEMM2(+dinv scale) -> AGG2(+b2)
// out[r] = dinv[r] * (sum_{e: row=r} hs[col_e] + hs[r]) + b   with hs = (X@W)*dinv
// ---------------------------------------------------------------------------

__global__ void count_kernel(const int* __restrict__ row, int E, int* __restrict__ deg) {
    int i = blockIdx.x * blockDim.x + threadIdx.x;
    int stride = gridDim.x * blockDim.x;
    for (; i < E; i += stride) atomicAdd(&deg[row[i]], 1);
}

__global__ void dinv_kernel(const int* __restrict__ deg, float* __restrict__ dinv, int N) {
    int i = blockIdx.x * blockDim.x + threadIdx.x;
    if (i < N) dinv[i] = rsqrtf((float)(deg[i] + 1));  // +1 = self loop
}

// block-local exclusive scan (256 per block) + block totals
__global__ void scan_block_kernel(const int* __restrict__ deg, int* __restrict__ off,
                                  int* __restrict__ bsum, int N) {
    __shared__ int s[256];
    int t = threadIdx.x, b = blockIdx.x, i = b * 256 + t;
    int v = (i < N) ? deg[i] : 0;
    s[t] = v; __syncthreads();
    #pragma unroll
    for (int d = 1; d < 256; d <<= 1) {
        int xv = (t >= d) ? s[t - d] : 0;
        __syncthreads();
        s[t] += xv;
        __syncthreads();
    }
    if (i < N) off[i] = s[t] - v;   // block-local exclusive
    if (t == 255) bsum[b] = s[255];
}

__global__ void scan_top_kernel(const int* __restrict__ bsum, int* __restrict__ boff, int nb) {
    __shared__ int s[256];
    int t = threadIdx.x;
    int v = (t < nb) ? bsum[t] : 0;
    s[t] = v; __syncthreads();
    #pragma unroll
    for (int d = 1; d < 256; d <<= 1) {
        int xv = (t >= d) ? s[t - d] : 0;
        __syncthreads();
        s[t] += xv;
        __syncthreads();
    }
    if (t < nb) boff[t] = s[t] - v;
}

__global__ void add_off_kernel(int* __restrict__ off, const int* __restrict__ boff,
                               int* __restrict__ cursor, int N, int E) {
    int i = blockIdx.x * 256 + threadIdx.x;
    if (i < N) {
        int v = off[i] + boff[blockIdx.x];
        off[i] = v;
        cursor[i] = v;
    }
    if (i == 0) off[N] = E;
}

__global__ void fill_kernel(const int* __restrict__ row, const int* __restrict__ col, int E,
                            int* __restrict__ cursor, int* __restrict__ csr) {
    int i = blockIdx.x * blockDim.x + threadIdx.x;
    int stride = gridDim.x * blockDim.x;
    for (; i < E; i += stride) {
        int r = row[i];
        int pos = atomicAdd(&cursor[r], 1);
        csr[pos] = col[i];
    }
}

// C = X(Nx128) @ W(128xCOUT), scaled by dinv[row]. Tile 64 rows x 64 cols.
__global__ __launch_bounds__(256) void gemm_scale_kernel(
    const float* __restrict__ X, const float* __restrict__ W,
    const float* __restrict__ dinv, float* __restrict__ out, int N, int COUT)
{
    __shared__ float Ws[128 * 64];   // full K for this 64-col tile
    __shared__ float As[16 * 68];    // 16 k x 64 rows, padded to 68

    const int t = threadIdx.x;
    const int row0 = blockIdx.x * 64;
    const int c0 = blockIdx.y * 64;

    for (int idx = t; idx < 128 * 64; idx += 256) {
        int k = idx >> 6, c = idx & 63;
        Ws[idx] = W[k * COUT + c0 + c];
    }

    const int ty = t >> 4, tx = t & 15;        // compute mapping: 4 rows x 4 cols
    const int m = t >> 2;                      // 0..63 staging row
    const int ksub = (t & 3) * 4;              // 0,4,8,12 staging k
    const int row_l = row0 + m;

    float acc[4][4] = {};
    for (int kt = 0; kt < 8; ++kt) {
        __syncthreads();   // As from previous iter fully consumed; also covers Ws on kt==0
        float4 a4 = make_float4(0.f, 0.f, 0.f, 0.f);
        if (row_l < N)
            a4 = *(const float4*)&X[(size_t)row_l * 128 + kt * 16 + ksub];
        As[(ksub + 0) * 68 + m] = a4.x;
        As[(ksub + 1) * 68 + m] = a4.y;
        As[(ksub + 2) * 68 + m] = a4.z;
        As[(ksub + 3) * 68 + m] = a4.w;
        __syncthreads();
        #pragma unroll
        for (int kk = 0; kk < 16; ++kk) {
            float4 a = *(const float4*)&As[kk * 68 + ty * 4];
            float4 w = *(const float4*)&Ws[(kt * 16 + kk) * 64 + tx * 4];
            acc[0][0] += a.x * w.x; acc[0][1] += a.x * w.y; acc[0][2] += a.x * w.z; acc[0][3] += a.x * w.w;
            acc[1][0] += a.y * w.x; acc[1][1] += a.y * w.y; acc[1][2] += a.y * w.z; acc[1][3] += a.y * w.w;
            acc[2][0] += a.z * w.x; acc[2][1] += a.z * w.y; acc[2][2] += a.z * w.z; acc[2][3] += a.z * w.w;
            acc[3][0] += a.w * w.x; acc[3][1] += a.w * w.y; acc[3][2] += a.w * w.z; acc[3][3] += a.w * w.w;
        }
    }

    #pragma unroll
    for (int i = 0; i < 4; ++i) {
        int r = row0 + ty * 4 + i;
        if (r < N) {
            float s = dinv[r];
            float4 o;
            o.x = acc[i][0] * s; o.y = acc[i][1] * s; o.z = acc[i][2] * s; o.w = acc[i][3] * s;
            *(float4*)&out[(size_t)r * COUT + c0 + tx * 4] = o;
        }
    }
}

// One block per node, one thread per channel.
template <bool RELU>
__global__ void agg_kernel(const float* __restrict__ hs, const int* __restrict__ csr,
                           const int* __restrict__ off, const float* __restrict__ dinv,
                           const float* __restrict__ bias, float* __restrict__ out,
                           int N, int C)
{
    int n = blockIdx.x;
    int c = threadIdx.x;
    float acc = hs[(size_t)n * C + c];          // self loop term (hs already *dinv)
    int s = off[n], e = off[n + 1];
    int j = s;
    for (; j + 1 < e; j += 2) {
        int c0 = csr[j], c1 = csr[j + 1];
        float v0 = hs[(size_t)c0 * C + c];
        float v1 = hs[(size_t)c1 * C + c];
        acc += v0;
        acc += v1;
    }
    if (j < e) acc += hs[(size_t)csr[j] * C + c];
    float v = dinv[n] * acc + bias[c];
    if (RELU) v = fmaxf(v, 0.0f);
    out[(size_t)n * C + c] = v;
}

extern "C" void kernel_launch(void* const* d_in, const int* in_sizes, int n_in,
                              void* d_out, int out_size, void* d_ws, size_t ws_size,
                              hipStream_t stream)
{
    const float* x  = (const float*)d_in[0];
    const int*   ei = (const int*)d_in[1];
    const float* W1 = (const float*)d_in[2];
    const float* b1 = (const float*)d_in[3];
    const float* W2 = (const float*)d_in[4];
    const float* b2 = (const float*)d_in[5];
    float* out = (float*)d_out;

    const int N = in_sizes[0] / 128;          // 50000
    const int E = in_sizes[1] / 2;            // 800000
    const int* row = ei;                       // targets
    const int* col = ei + E;                   // sources

    // workspace layout (256B aligned)
    char* ws = (char*)d_ws;
    size_t o = 0;
    auto take = [&](size_t bytes) { void* p = ws + o; o = (o + bytes + 255) & ~(size_t)255; return p; };
    int*   deg    = (int*)  take((size_t)N * 4);
    float* dinv   = (float*)take((size_t)N * 4);
    int*   off    = (int*)  take((size_t)(N + 1) * 4);
    int*   cursor = (int*)  take((size_t)N * 4);
    int*   bsum   = (int*)  take(1024);
    int*   boff   = (int*)  take(1024);
    int*   csr    = (int*)  take((size_t)E * 4);
    float* hs     = (float*)take((size_t)N * 128 * 4);   // layer-1 transformed; reused as hs2
    float* a1     = (float*)take((size_t)N * 128 * 4);   // layer-1 activations
    float* hs2    = hs;                                   // alias: hs dead after agg1

    const int nb = (N + 255) / 256;           // 196 scan blocks

    hipMemsetAsync(deg, 0, (size_t)N * 4, stream);
    count_kernel<<<2048, 256, 0, stream>>>(row, E, deg);
    dinv_kernel<<<(N + 255) / 256, 256, 0, stream>>>(deg, dinv, N);
    scan_block_kernel<<<nb, 256, 0, stream>>>(deg, off, bsum, N);
    scan_top_kernel<<<1, 256, 0, stream>>>(bsum, boff, nb);
    add_off_kernel<<<nb, 256, 0, stream>>>(off, boff, cursor, N, E);
    fill_kernel<<<2048, 256, 0, stream>>>(row, col, E, cursor, csr);

    // layer 1: hs = (x @ W1) * dinv ; a1 = relu(dinv*(sum hs[col] + hs[n]) + b1)
    gemm_scale_kernel<<<dim3((N + 63) / 64, 2), 256, 0, stream>>>(x, W1, dinv, hs, N, 128);
    agg_kernel<true><<<N, 128, 0, stream>>>(hs, csr, off, dinv, b1, a1, N, 128);

    // layer 2: hs2 = (a1 @ W2) * dinv ; out = dinv*(sum hs2[col] + hs2[n]) + b2
    gemm_scale_kernel<<<dim3((N + 63) / 64, 1), 256, 0, stream>>>(a1, W2, dinv, hs2, N, 64);
    agg_kernel<false><<<N, 64, 0, stream>>>(hs2, csr, off, dinv, b2, out, N, 64);
}

// Round 2
// 222.242 us; speedup vs baseline: 1.1457x; 1.1457x over previous
//
#include <hip/hip_runtime.h>

// ---------------------------------------------------------------------------
// GCN 2-layer encoder for MI355X.
//   deg -> CSR (count, scan+dinv, fill) -> GEMM1(->bf16, *dinv) -> AGG1(+b1,relu, f32 out)
//   -> GEMM2(->bf16, *dinv) -> AGG2(+b2, f32 out)
// out[r] = dinv[r] * (sum_{e: row=r} hs[col_e] + hs[r]) + b   with hs = (X@W)*dinv
// hs tables stored bf16 to halve gather traffic; all accumulation in f32.
// ---------------------------------------------------------------------------

__device__ __forceinline__ float bf2f(unsigned int u16) {
    return __uint_as_float(u16 << 16);
}
__device__ __forceinline__ unsigned int f2bf_rne(float f) {
    unsigned int u = __float_as_uint(f);
    return (u + 0x7fffu + ((u >> 16) & 1u)) >> 16;
}
__device__ __forceinline__ unsigned int pack2bf(float a, float b) {
    return f2bf_rne(a) | (f2bf_rne(b) << 16);
}

__global__ void count_kernel(const int* __restrict__ row, int E, int* __restrict__ deg) {
    int i = blockIdx.x * blockDim.x + threadIdx.x;
    int stride = gridDim.x * blockDim.x;
    for (; i < E; i += stride) atomicAdd(&deg[row[i]], 1);
}

// block-local exclusive scan (256 per block) + block totals; also emits dinv
__global__ void scan_block_kernel(const int* __restrict__ deg, int* __restrict__ off,
                                  int* __restrict__ bsum, float* __restrict__ dinv, int N) {
    __shared__ int s[256];
    int t = threadIdx.x, b = blockIdx.x, i = b * 256 + t;
    int v = (i < N) ? deg[i] : 0;
    if (i < N) dinv[i] = rsqrtf((float)(v + 1));   // +1 self loop
    s[t] = v; __syncthreads();
    #pragma unroll
    for (int d = 1; d < 256; d <<= 1) {
        int xv = (t >= d) ? s[t - d] : 0;
        __syncthreads();
        s[t] += xv;
        __syncthreads();
    }
    if (i < N) off[i] = s[t] - v;   // block-local exclusive
    if (t == 255) bsum[b] = s[255];
}

__global__ void scan_top_kernel(const int* __restrict__ bsum, int* __restrict__ boff, int nb) {
    __shared__ int s[256];
    int t = threadIdx.x;
    int v = (t < nb) ? bsum[t] : 0;
    s[t] = v; __syncthreads();
    #pragma unroll
    for (int d = 1; d < 256; d <<= 1) {
        int xv = (t >= d) ? s[t - d] : 0;
        __syncthreads();
        s[t] += xv;
        __syncthreads();
    }
    if (t < nb) boff[t] = s[t] - v;
}

__global__ void add_off_kernel(int* __restrict__ off, const int* __restrict__ boff,
                               int* __restrict__ cursor, int N, int E) {
    int i = blockIdx.x * 256 + threadIdx.x;
    if (i < N) {
        int v = off[i] + boff[blockIdx.x];
        off[i] = v;
        cursor[i] = v;
    }
    if (i == 0) off[N] = E;
}

__global__ void fill_kernel(const int* __restrict__ row, const int* __restrict__ col, int E,
                            int* __restrict__ cursor, int* __restrict__ csr) {
    int i = blockIdx.x * blockDim.x + threadIdx.x;
    int stride = gridDim.x * blockDim.x;
    for (; i < E; i += stride) {
        int r = row[i];
        int pos = atomicAdd(&cursor[r], 1);
        csr[pos] = col[i];
    }
}

// C = X(Nx128) @ W(128xCOUT), scaled by dinv[row], stored bf16. 64x64 tile.
__global__ __launch_bounds__(256) void gemm_scale_kernel(
    const float* __restrict__ X, const float* __restrict__ W,
    const float* __restrict__ dinv, unsigned short* __restrict__ out, int N, int COUT)
{
    __shared__ float Ws[128 * 64];   // full K for this 64-col tile
    __shared__ float As[16 * 68];    // 16 k x 64 rows, padded to 68

    const int t = threadIdx.x;
    const int row0 = blockIdx.x * 64;
    const int c0 = blockIdx.y * 64;

    for (int idx = t; idx < 128 * 64; idx += 256) {
        int k = idx >> 6, c = idx & 63;
        Ws[idx] = W[k * COUT + c0 + c];
    }

    const int ty = t >> 4, tx = t & 15;        // compute mapping: 4 rows x 4 cols
    const int m = t >> 2;                      // 0..63 staging row
    const int ksub = (t & 3) * 4;              // 0,4,8,12 staging k
    const int row_l = row0 + m;

    float acc[4][4] = {};
    for (int kt = 0; kt < 8; ++kt) {
        __syncthreads();
        float4 a4 = make_float4(0.f, 0.f, 0.f, 0.f);
        if (row_l < N)
            a4 = *(const float4*)&X[(size_t)row_l * 128 + kt * 16 + ksub];
        As[(ksub + 0) * 68 + m] = a4.x;
        As[(ksub + 1) * 68 + m] = a4.y;
        As[(ksub + 2) * 68 + m] = a4.z;
        As[(ksub + 3) * 68 + m] = a4.w;
        __syncthreads();
        #pragma unroll
        for (int kk = 0; kk < 16; ++kk) {
            float4 a = *(const float4*)&As[kk * 68 + ty * 4];
            float4 w = *(const float4*)&Ws[(kt * 16 + kk) * 64 + tx * 4];
            acc[0][0] += a.x * w.x; acc[0][1] += a.x * w.y; acc[0][2] += a.x * w.z; acc[0][3] += a.x * w.w;
            acc[1][0] += a.y * w.x; acc[1][1] += a.y * w.y; acc[1][2] += a.y * w.z; acc[1][3] += a.y * w.w;
            acc[2][0] += a.z * w.x; acc[2][1] += a.z * w.y; acc[2][2] += a.z * w.z; acc[2][3] += a.z * w.w;
            acc[3][0] += a.w * w.x; acc[3][1] += a.w * w.y; acc[3][2] += a.w * w.z; acc[3][3] += a.w * w.w;
        }
    }

    #pragma unroll
    for (int i = 0; i < 4; ++i) {
        int r = row0 + ty * 4 + i;
        if (r < N) {
            float s = dinv[r];
            uint2 o;
            o.x = pack2bf(acc[i][0] * s, acc[i][1] * s);
            o.y = pack2bf(acc[i][2] * s, acc[i][3] * s);
            *(uint2*)&out[(size_t)r * COUT + c0 + tx * 4] = o;
        }
    }
}

// AGG layer 1: C=128, one wave per node, lane l owns channels {2l, 2l+1}.
// a1 = relu(dinv*(sum hs[col] + hs[n]) + b1), f32 output.
__global__ __launch_bounds__(64) void agg1_kernel(
    const unsigned short* __restrict__ hs, const int* __restrict__ csr,
    const int* __restrict__ off, const float* __restrict__ dinv,
    const float* __restrict__ bias, float* __restrict__ out, int N)
{
    const int n = blockIdx.x;
    const int ch = threadIdx.x * 2;

    unsigned int sv = *(const unsigned int*)&hs[(size_t)n * 128 + ch];  // self loop
    float ax = bf2f(sv & 0xffffu), ay = bf2f(sv >> 16);

    int s = off[n], e = off[n + 1];
    int j = s;
    for (; j + 3 < e; j += 4) {
        int c0 = csr[j], c1 = csr[j + 1], c2 = csr[j + 2], c3 = csr[j + 3];
        unsigned int v0 = *(const unsigned int*)&hs[(size_t)c0 * 128 + ch];
        unsigned int v1 = *(const unsigned int*)&hs[(size_t)c1 * 128 + ch];
        unsigned int v2 = *(const unsigned int*)&hs[(size_t)c2 * 128 + ch];
        unsigned int v3 = *(const unsigned int*)&hs[(size_t)c3 * 128 + ch];
        ax += bf2f(v0 & 0xffffu); ay += bf2f(v0 >> 16);
        ax += bf2f(v1 & 0xffffu); ay += bf2f(v1 >> 16);
        ax += bf2f(v2 & 0xffffu); ay += bf2f(v2 >> 16);
        ax += bf2f(v3 & 0xffffu); ay += bf2f(v3 >> 16);
    }
    for (; j < e; ++j) {
        unsigned int v = *(const unsigned int*)&hs[(size_t)csr[j] * 128 + ch];
        ax += bf2f(v & 0xffffu); ay += bf2f(v >> 16);
    }

    float d = dinv[n];
    float2 b = *(const float2*)&bias[ch];
    float2 o;
    o.x = fmaxf(d * ax + b.x, 0.0f);
    o.y = fmaxf(d * ay + b.y, 0.0f);
    *(float2*)&out[(size_t)n * 128 + ch] = o;
}

// AGG layer 2: C=64, one wave per node; lanes 0-31 process edge j, lanes 32-63
// edge j+1 (each half-wave covers the 128B row as 32 x uint). Combine via shfl.
__global__ __launch_bounds__(64) void agg2_kernel(
    const unsigned short* __restrict__ hs, const int* __restrict__ csr,
    const int* __restrict__ off, const float* __restrict__ dinv,
    const float* __restrict__ bias, float* __restrict__ out, int N)
{
    const int n = blockIdx.x;
    const int l = threadIdx.x;
    const int half = l >> 5;
    const int ch = (l & 31) * 2;

    int s = off[n], e = off[n + 1];
    float ax = 0.f, ay = 0.f;
    int j = s;
    for (; j + 3 < e; j += 4) {
        int c0 = csr[j + half];
        int c1 = csr[j + 2 + half];
        unsigned int v0 = *(const unsigned int*)&hs[(size_t)c0 * 64 + ch];
        unsigned int v1 = *(const unsigned int*)&hs[(size_t)c1 * 64 + ch];
        ax += bf2f(v0 & 0xffffu); ay += bf2f(v0 >> 16);
        ax += bf2f(v1 & 0xffffu); ay += bf2f(v1 >> 16);
    }
    if (j + 1 < e) {
        int c = csr[j + half];
        unsigned int v = *(const unsigned int*)&hs[(size_t)c * 64 + ch];
        ax += bf2f(v & 0xffffu); ay += bf2f(v >> 16);
        j += 2;
    }
    if (j < e && half == 0) {   // odd tail edge: lower half only
        unsigned int v = *(const unsigned int*)&hs[(size_t)csr[j] * 64 + ch];
        ax += bf2f(v & 0xffffu); ay += bf2f(v >> 16);
    }

    ax += __shfl_xor(ax, 32);
    ay += __shfl_xor(ay, 32);

    if (half == 0) {
        unsigned int sv = *(const unsigned int*)&hs[(size_t)n * 64 + ch];  // self loop
        ax += bf2f(sv & 0xffffu); ay += bf2f(sv >> 16);
        float d = dinv[n];
        float2 b = *(const float2*)&bias[ch];
        float2 o;
        o.x = d * ax + b.x;
        o.y = d * ay + b.y;
        *(float2*)&out[(size_t)n * 64 + ch] = o;
    }
}

extern "C" void kernel_launch(void* const* d_in, const int* in_sizes, int n_in,
                              void* d_out, int out_size, void* d_ws, size_t ws_size,
                              hipStream_t stream)
{
    const float* x  = (const float*)d_in[0];
    const int*   ei = (const int*)d_in[1];
    const float* W1 = (const float*)d_in[2];
    const float* b1 = (const float*)d_in[3];
    const float* W2 = (const float*)d_in[4];
    const float* b2 = (const float*)d_in[5];
    float* out = (float*)d_out;

    const int N = in_sizes[0] / 128;          // 50000
    const int E = in_sizes[1] / 2;            // 800000
    const int* row = ei;                       // targets
    const int* col = ei + E;                   // sources

    // workspace layout (256B aligned)
    char* ws = (char*)d_ws;
    size_t o = 0;
    auto take = [&](size_t bytes) { void* p = ws + o; o = (o + bytes + 255) & ~(size_t)255; return p; };
    int*   deg    = (int*)  take((size_t)N * 4);
    float* dinv   = (float*)take((size_t)N * 4);
    int*   off    = (int*)  take((size_t)(N + 1) * 4);
    int*   cursor = (int*)  take((size_t)N * 4);
    int*   bsum   = (int*)  take(1024);
    int*   boff   = (int*)  take(1024);
    int*   csr    = (int*)  take((size_t)E * 4);
    unsigned short* hs  = (unsigned short*)take((size_t)N * 128 * 2);  // bf16, reused as hs2
    float* a1     = (float*)take((size_t)N * 128 * 4);                  // layer-1 activations f32
    unsigned short* hs2 = hs;                                           // alias: hs dead after agg1

    const int nb = (N + 255) / 256;           // 196 scan blocks

    hipMemsetAsync(deg, 0, (size_t)N * 4, stream);
    count_kernel<<<2048, 256, 0, stream>>>(row, E, deg);
    scan_block_kernel<<<nb, 256, 0, stream>>>(deg, off, bsum, dinv, N);
    scan_top_kernel<<<1, 256, 0, stream>>>(bsum, boff, nb);
    add_off_kernel<<<nb, 256, 0, stream>>>(off, boff, cursor, N, E);
    fill_kernel<<<2048, 256, 0, stream>>>(row, col, E, cursor, csr);

    // layer 1: hs = bf16((x @ W1) * dinv) ; a1 = relu(dinv*(sum hs[col] + hs[n]) + b1)
    gemm_scale_kernel<<<dim3((N + 63) / 64, 2), 256, 0, stream>>>(x, W1, dinv, hs, N, 128);
    agg1_kernel<<<N, 64, 0, stream>>>(hs, csr, off, dinv, b1, a1, N);

    // layer 2: hs2 = bf16((a1 @ W2) * dinv) ; out = dinv*(sum hs2[col] + hs2[n]) + b2
    gemm_scale_kernel<<<dim3((N + 63) / 64, 1), 256, 0, stream>>>(a1, W2, dinv, hs2, N, 64);
    agg2_kernel<<<N, 64, 0, stream>>>(hs2, csr, off, dinv, b2, out, N);
}